// Round 8
// baseline (67.554 us; speedup 1.0000x reference)
//
#include <hip/hip_runtime.h>
#include <hip/hip_bf16.h>
#include <math.h>

#define DD     128
#define BROWS  64          // rows per block
#define NWAVE  4
#define TPB    (NWAVE*64)  // 256 threads
#define XSTR   132         // bf16 elems per LDS row (264B: 8B-aligned, 2-way-free banks)
#define MAXBLK 8192

typedef __attribute__((ext_vector_type(8)))  short bf16x8;
typedef __attribute__((ext_vector_type(16))) float f32x16;

// static device scratch (rewritten every launch -> deterministic)
// layout: [L][T][ks][mt][lane][8]  (L=layer, T=hi/lo, ks=k-step of 16, mt=32-feature tile)
__device__ __align__(16) unsigned short g_wfrag[2*2*8*4*64*8]; // 128 KB
__device__ __align__(16) float g_b1p[DD];
__device__ float g_m, g_invZ;
__device__ float g_pm[MAXBLK], g_ps[MAXBLK];

__device__ __forceinline__ unsigned short f2b(float x){
    union { __hip_bfloat16 b; unsigned short u; } c;
    c.b = __float2bfloat16(x);
    return c.u;
}

// truncation-hi split: hi = upper 16 bits of f32 (exact float = bits&0xFFFF0000),
// lo = RNE-bf16(x - hi). |lo| <= 2^-8|x|, residual after lo-round <= 2^-17|x|.
__device__ __forceinline__ void split2(float x, unsigned short& h, unsigned short& l){
    unsigned int bx = __float_as_uint(x);
    float hf = __uint_as_float(bx & 0xFFFF0000u);
    h = (unsigned short)(bx >> 16);
    l = f2b(x - hf);
}

// load a bf16x8 B-frag as two 8B chunks (264B row stride is 8B-aligned only)
__device__ __forceinline__ bf16x8 ldB(const unsigned short* p){
    union { ushort4 u[2]; bf16x8 v; } c;
    c.u[0] = *(const ushort4*)p;
    c.u[1] = *(const ushort4*)(p + 4);
    return c.v;
}

// ---- prep: split W1(:,0:128), W2 into bf16 hi/lo in 32x32x16 A-frag order ----
// A-frag: lane l holds A[m = mt*32 + (l&31)][k = ks*16 + (l>>5)*8 + r], r=0..7
__global__ __launch_bounds__(256)
void k_wprep(const float* __restrict__ W1, const float* __restrict__ W2)
{
    const int t    = blockIdx.x*256 + threadIdx.x;   // 0..8191
    const int lane = t & 63;
    const int mt   = (t>>6) & 3;
    const int ks   = (t>>8) & 7;
    const int T    = (t>>11) & 1;                    // 0 = hi, 1 = lo
    const int L    = (t>>12) & 1;                    // 0 = layer1, 1 = layer2
    const int col  = mt*32 + (lane & 31);
    const int kb   = ks*16 + ((lane>>5) << 3);
    const float* src = L ? (W2 + (size_t)col*128 + kb) : (W1 + (size_t)col*256 + kb);
    unsigned short o[8];
    #pragma unroll
    for (int r = 0; r < 8; ++r){
        float x = src[r];
        unsigned short h, l;
        split2(x, h, l);
        o[r] = T ? l : h;
    }
    ushort4* dst = (ushort4*)&g_wfrag[(size_t)t * 8];
    dst[0] = *(ushort4*)&o[0];
    dst[1] = *(ushort4*)&o[4];
}

// ---- prep: fold u_rep half of layer1 into bias (exact fp32) ----
__global__ __launch_bounds__(128)
void k_b1p(const float* __restrict__ W1, const float* __restrict__ b1,
           const float* __restrict__ u)
{
    const int c = threadIdx.x;
    float a = b1[c];
    for (int j = 0; j < 128; ++j) a = fmaf(W1[(size_t)c*256 + 128 + j], u[j], a);
    g_b1p[c] = a;
}

// One layer, m-split: this wave's 32 features (mt = w) for all 64 rows.
// A register-resident (pinned); B streams from LDS.
__device__ __forceinline__ void layer_compute(
    const bf16x8 (&Ah)[8], const bf16x8 (&Al)[8],
    const unsigned short (&Xh)[BROWS*XSTR],
    const unsigned short (&Xl)[BROWS*XSTR],
    const float* __restrict__ bias,
    f32x16 (&acc)[2], int lane, int w)
{
    const int hg = lane >> 5;
    #pragma unroll
    for (int qq = 0; qq < 4; ++qq){
        const float4 bv = *(const float4*)&bias[w*32 + qq*8 + (hg<<2)];
        #pragma unroll
        for (int nt = 0; nt < 2; ++nt){
            acc[nt][qq*4+0] = bv.x; acc[nt][qq*4+1] = bv.y;
            acc[nt][qq*4+2] = bv.z; acc[nt][qq*4+3] = bv.w;
        }
    }
    #pragma unroll
    for (int ks = 0; ks < 8; ++ks){
        const int koff = ks*16 + (hg<<3);
        #pragma unroll
        for (int nt = 0; nt < 2; ++nt){
            const int row = nt*32 + (lane & 31);
            const bf16x8 Bh = ldB(&Xh[row*XSTR + koff]);
            const bf16x8 Bl = ldB(&Xl[row*XSTR + koff]);
            acc[nt] = __builtin_amdgcn_mfma_f32_32x32x16_bf16(Ah[ks], Bh, acc[nt], 0,0,0);
            acc[nt] = __builtin_amdgcn_mfma_f32_32x32x16_bf16(Ah[ks], Bl, acc[nt], 0,0,0);
            acc[nt] = __builtin_amdgcn_mfma_f32_32x32x16_bf16(Al[ks], Bh, acc[nt], 0,0,0);
        }
    }
}

__global__ __launch_bounds__(TPB, 3)
void k_mlp(const float* __restrict__ node1,
           const float* __restrict__ b2,
           const float* __restrict__ W3,
           float* __restrict__ out, int n)
{
    __shared__ unsigned short Xh[BROWS*XSTR];   // 16896 B
    __shared__ unsigned short Xl[BROWS*XSTR];   // 16896 B
    __shared__ float Ps[NWAVE][BROWS];          // 1 KB layer-3 partials
    const int tid   = threadIdx.x;
    const int lane  = tid & 63;
    const int w     = __builtin_amdgcn_readfirstlane(tid >> 6);
    const int hg    = lane >> 5;
    const int r0    = blockIdx.x * BROWS;

    const bf16x8* wf = (const bf16x8*)g_wfrag;

    // ---- issue A-frags for layer 1 FIRST (latency hides under x staging) ----
    bf16x8 A1h[8], A1l[8];
    #pragma unroll
    for (int ks = 0; ks < 8; ++ks){
        A1h[ks] = wf[((0*8 + ks)*4 + w)*64 + lane];   // L=0,T=hi
        A1l[ks] = wf[((1*8 + ks)*4 + w)*64 + lane];   // L=0,T=lo
    }

    // ---- stage x tile: 64 rows x 128 k, split to bf16 hi/lo in LDS ----
    #pragma unroll
    for (int i = 0; i < 8; ++i){
        int idx = i*TPB + tid;            // 0..2047 float4 slots (= row*32 + kq)
        int row = idx >> 5, kq = idx & 31;
        float4 v = {0.f, 0.f, 0.f, 0.f};
        if (r0 + row < n) v = reinterpret_cast<const float4*>(node1)[(size_t)(r0+row)*32 + kq];
        ushort4 hv, lv;
        split2(v.x, hv.x, lv.x);
        split2(v.y, hv.y, lv.y);
        split2(v.z, hv.z, lv.z);
        split2(v.w, hv.w, lv.w);
        *(ushort4*)&Xh[row*XSTR + kq*4] = hv;
        *(ushort4*)&Xl[row*XSTR + kq*4] = lv;
    }

    // pin A1 in registers: opaque asm output cannot be sunk or rematerialized
    #pragma unroll
    for (int ks = 0; ks < 8; ++ks){
        asm volatile("" : "+v"(A1h[ks]), "+v"(A1l[ks]));
    }
    __syncthreads();

    f32x16 acc[2];

    // ---- layer 1 ----
    layer_compute(A1h, A1l, Xh, Xl, g_b1p, acc, lane, w);

    // ---- A-frags for layer 2: issue + pin now; latency drains under writeback ----
    bf16x8 A2h[8], A2l[8];
    #pragma unroll
    for (int ks = 0; ks < 8; ++ks){
        A2h[ks] = wf[((2*8 + ks)*4 + w)*64 + lane];   // L=1,T=hi
        A2l[ks] = wf[((3*8 + ks)*4 + w)*64 + lane];   // L=1,T=lo
    }
    #pragma unroll
    for (int ks = 0; ks < 8; ++ks){
        asm volatile("" : "+v"(A2h[ks]), "+v"(A2l[ks]));
    }

    __syncthreads();   // everyone done READING X

    // relu + bf16-split writeback: wave w writes features [32w,32w+32) for all rows
    #pragma unroll
    for (int nt = 0; nt < 2; ++nt){
        const int row = nt*32 + (lane & 31);
        #pragma unroll
        for (int qq = 0; qq < 4; ++qq){
            const int c = w*32 + qq*8 + (hg<<2);
            ushort4 hv, lv;
            float v;
            v = fmaxf(acc[nt][qq*4+0], 0.f); split2(v, hv.x, lv.x);
            v = fmaxf(acc[nt][qq*4+1], 0.f); split2(v, hv.y, lv.y);
            v = fmaxf(acc[nt][qq*4+2], 0.f); split2(v, hv.z, lv.z);
            v = fmaxf(acc[nt][qq*4+3], 0.f); split2(v, hv.w, lv.w);
            *(ushort4*)&Xh[row*XSTR + c] = hv;
            *(ushort4*)&Xl[row*XSTR + c] = lv;
        }
    }
    __syncthreads();   // h1 fully written

    // ---- layer 2 ----
    layer_compute(A2h, A2l, Xh, Xl, b2, acc, lane, w);

    // ---- layer 3: per-wave partial over its 32 features ----
    float p[2] = {0.f, 0.f};
    #pragma unroll
    for (int qq = 0; qq < 4; ++qq){
        const float4 wv = *(const float4*)&W3[w*32 + qq*8 + (hg<<2)];
        #pragma unroll
        for (int nt = 0; nt < 2; ++nt){
            p[nt] = fmaf(fmaxf(acc[nt][qq*4+0], 0.f), wv.x, p[nt]);
            p[nt] = fmaf(fmaxf(acc[nt][qq*4+1], 0.f), wv.y, p[nt]);
            p[nt] = fmaf(fmaxf(acc[nt][qq*4+2], 0.f), wv.z, p[nt]);
            p[nt] = fmaf(fmaxf(acc[nt][qq*4+3], 0.f), wv.w, p[nt]);
        }
    }
    #pragma unroll
    for (int nt = 0; nt < 2; ++nt){
        p[nt] += __shfl_xor(p[nt], 32);
        if (lane < 32) Ps[w][nt*32 + lane] = p[nt];
    }
    __syncthreads();

    // ---- cross-wave feature reduction + per-block softmax stats (wave 0) ----
    if (w == 0){
        const int ra = r0 + lane;
        const bool va = ra < n;
        const float s = Ps[0][lane] + Ps[1][lane] + Ps[2][lane] + Ps[3][lane];
        if (va) out[ra] = s;
        float m = va ? s : -3.0e38f;
        #pragma unroll
        for (int off = 32; off > 0; off >>= 1) m = fmaxf(m, __shfl_xor(m, off));
        float e = va ? expf(s - m) : 0.f;
        #pragma unroll
        for (int off = 32; off > 0; off >>= 1) e += __shfl_xor(e, off);
        if (lane == 0){ g_pm[blockIdx.x] = m; g_ps[blockIdx.x] = e; }
    }
}

__global__ __launch_bounds__(1024)
void k_combine(int ng)
{
    __shared__ float red[17];
    const int tid = threadIdx.x, lane = tid & 63, wv = tid >> 6;

    float m = -3.0e38f;
    for (int i = tid; i < ng; i += 1024) m = fmaxf(m, g_pm[i]);
    #pragma unroll
    for (int off = 32; off > 0; off >>= 1) m = fmaxf(m, __shfl_xor(m, off));
    if (lane == 0) red[wv] = m;
    __syncthreads();
    if (tid < 64){
        float v = (lane < 16) ? red[lane] : -3.0e38f;
        #pragma unroll
        for (int off = 32; off > 0; off >>= 1) v = fmaxf(v, __shfl_xor(v, off));
        if (lane == 0) red[16] = v;
    }
    __syncthreads();
    m = red[16];

    float z = 0.f;
    for (int i = tid; i < ng; i += 1024) z += g_ps[i] * expf(g_pm[i] - m);
    #pragma unroll
    for (int off = 32; off > 0; off >>= 1) z += __shfl_xor(z, off);
    __syncthreads();
    if (lane == 0) red[wv] = z;
    __syncthreads();
    if (tid < 64){
        float v = (lane < 16) ? red[lane] : 0.f;
        #pragma unroll
        for (int off = 32; off > 0; off >>= 1) v += __shfl_xor(v, off);
        if (lane == 0){ g_m = m; g_invZ = 1.0f / v; }
    }
}

__global__ __launch_bounds__(256)
void k_norm(float* __restrict__ s, int n)
{
    const int i = blockIdx.x * 256 + threadIdx.x;
    const float m = g_m, r = g_invZ;
    const int n4 = n >> 2;
    if (i < n4){
        float4 v = reinterpret_cast<float4*>(s)[i];
        v.x = expf(v.x - m) * r;
        v.y = expf(v.y - m) * r;
        v.z = expf(v.z - m) * r;
        v.w = expf(v.w - m) * r;
        reinterpret_cast<float4*>(s)[i] = v;
    }
    const int rem = n - (n4 << 2);
    if (i < rem){
        int t = (n4 << 2) + i;
        s[t] = expf(s[t] - m) * r;
    }
}

extern "C" void kernel_launch(void* const* d_in, const int* in_sizes, int n_in,
                              void* d_out, int out_size, void* d_ws, size_t ws_size,
                              hipStream_t stream)
{
    const float* node1 = (const float*)d_in[0];
    const float* urep  = (const float*)d_in[1];
    const float* W1    = (const float*)d_in[3];
    const float* b1    = (const float*)d_in[4];
    const float* W2    = (const float*)d_in[5];
    const float* b2    = (const float*)d_in[6];
    const float* W3    = (const float*)d_in[7];
    float* out = (float*)d_out;

    const int n    = in_sizes[0] / DD;            // 200000
    const int nblk = (n + BROWS - 1) / BROWS;     // 3125
    const int ng   = nblk;

    k_wprep<<<dim3(32), dim3(256), 0, stream>>>(W1, W2);
    k_b1p<<<dim3(1), dim3(128), 0, stream>>>(W1, b1, urep);
    k_mlp<<<dim3(nblk), dim3(TPB), 0, stream>>>(node1, b2, W3, out, n);
    k_combine<<<dim3(1), dim3(1024), 0, stream>>>(ng);

    const int n4  = n >> 2;
    const int nb3 = (n4 + 255) / 256 > 0 ? (n4 + 255) / 256 : 1;
    k_norm<<<dim3(nb3), dim3(256), 0, stream>>>(out, n);
}

// Round 9
// 64.904 us; speedup vs baseline: 1.0408x; 1.0408x over previous
//
#include <hip/hip_runtime.h>
#include <hip/hip_bf16.h>
#include <math.h>

#define DD     128
#define BROWS  64          // rows per block
#define NWAVE  4
#define TPB    (NWAVE*64)  // 256 threads
#define XSTR   132         // bf16 elems per LDS row (264B: 8B-aligned, 2-way-free banks)
#define MAXBLK 8192

typedef __attribute__((ext_vector_type(8)))  short bf16x8;
typedef __attribute__((ext_vector_type(4)))  float f32x4;
typedef __attribute__((ext_vector_type(16))) float f32x16;

// static device scratch (rewritten every launch -> deterministic)
// layout: [L][T][ks][mt][lane][8]  (L=layer, T=hi/lo, ks=k-step of 16, mt=32-feature tile)
__device__ __align__(16) unsigned short g_wfrag[2*2*8*4*64*8]; // 128 KB
__device__ __align__(16) float g_b1p[DD];
__device__ float g_m, g_invZ;
__device__ float g_pm[MAXBLK], g_ps[MAXBLK];

__device__ __forceinline__ unsigned short f2b(float x){
    union { __hip_bfloat16 b; unsigned short u; } c;
    c.b = __float2bfloat16(x);
    return c.u;
}

// truncation-hi split: hi = upper 16 bits of f32 (exact float = bits&0xFFFF0000),
// lo = RNE-bf16(x - hi). |lo| <= 2^-8|x|, residual after lo-round <= 2^-17|x|.
__device__ __forceinline__ void split2(float x, unsigned short& h, unsigned short& l){
    unsigned int bx = __float_as_uint(x);
    float hf = __uint_as_float(bx & 0xFFFF0000u);
    h = (unsigned short)(bx >> 16);
    l = f2b(x - hf);
}

// load a bf16x8 B-frag as two 8B chunks (264B row stride is 8B-aligned only)
__device__ __forceinline__ bf16x8 ldB(const unsigned short* p){
    union { ushort4 u[2]; bf16x8 v; } c;
    c.u[0] = *(const ushort4*)p;
    c.u[1] = *(const ushort4*)(p + 4);
    return c.v;
}

// ---- prep: split W1(:,0:128), W2 into bf16 hi/lo in 32x32x16 A-frag order ----
// A-frag: lane l holds A[m = mt*32 + (l&31)][k = ks*16 + (l>>5)*8 + r], r=0..7
__global__ __launch_bounds__(256)
void k_wprep(const float* __restrict__ W1, const float* __restrict__ W2)
{
    const int t    = blockIdx.x*256 + threadIdx.x;   // 0..8191
    const int lane = t & 63;
    const int mt   = (t>>6) & 3;
    const int ks   = (t>>8) & 7;
    const int T    = (t>>11) & 1;                    // 0 = hi, 1 = lo
    const int L    = (t>>12) & 1;                    // 0 = layer1, 1 = layer2
    const int col  = mt*32 + (lane & 31);
    const int kb   = ks*16 + ((lane>>5) << 3);
    const float* src = L ? (W2 + (size_t)col*128 + kb) : (W1 + (size_t)col*256 + kb);
    unsigned short o[8];
    #pragma unroll
    for (int r = 0; r < 8; ++r){
        float x = src[r];
        unsigned short h, l;
        split2(x, h, l);
        o[r] = T ? l : h;
    }
    ushort4* dst = (ushort4*)&g_wfrag[(size_t)t * 8];
    dst[0] = *(ushort4*)&o[0];
    dst[1] = *(ushort4*)&o[4];
}

// ---- prep: fold u_rep half of layer1 into bias (exact fp32) ----
__global__ __launch_bounds__(128)
void k_b1p(const float* __restrict__ W1, const float* __restrict__ b1,
           const float* __restrict__ u)
{
    const int c = threadIdx.x;
    float a = b1[c];
    for (int j = 0; j < 128; ++j) a = fmaf(W1[(size_t)c*256 + 128 + j], u[j], a);
    g_b1p[c] = a;
}

// One layer, m-split: this wave's 32 features (mt = w) for all 64 rows.
__device__ __forceinline__ void layer_compute(
    const bf16x8 (&Ah)[8], const bf16x8 (&Al)[8],
    const unsigned short (&Xh)[BROWS*XSTR],
    const unsigned short (&Xl)[BROWS*XSTR],
    const float* __restrict__ bias,
    f32x16 (&acc)[2], int lane, int w)
{
    const int hg = lane >> 5;
    #pragma unroll
    for (int qq = 0; qq < 4; ++qq){
        const float4 bv = *(const float4*)&bias[w*32 + qq*8 + (hg<<2)];
        #pragma unroll
        for (int nt = 0; nt < 2; ++nt){
            acc[nt][qq*4+0] = bv.x; acc[nt][qq*4+1] = bv.y;
            acc[nt][qq*4+2] = bv.z; acc[nt][qq*4+3] = bv.w;
        }
    }
    #pragma unroll
    for (int ks = 0; ks < 8; ++ks){
        const int koff = ks*16 + (hg<<3);
        #pragma unroll
        for (int nt = 0; nt < 2; ++nt){
            const int row = nt*32 + (lane & 31);
            const bf16x8 Bh = ldB(&Xh[row*XSTR + koff]);
            const bf16x8 Bl = ldB(&Xl[row*XSTR + koff]);
            acc[nt] = __builtin_amdgcn_mfma_f32_32x32x16_bf16(Ah[ks], Bh, acc[nt], 0,0,0);
            acc[nt] = __builtin_amdgcn_mfma_f32_32x32x16_bf16(Ah[ks], Bl, acc[nt], 0,0,0);
            acc[nt] = __builtin_amdgcn_mfma_f32_32x32x16_bf16(Al[ks], Bh, acc[nt], 0,0,0);
        }
    }
}

__global__ __launch_bounds__(TPB, 3)
void k_mlp(const float* __restrict__ node1,
           const float* __restrict__ b2,
           const float* __restrict__ W3,
           float* __restrict__ out, int n)
{
    __shared__ unsigned short Xh[BROWS*XSTR];   // 16896 B
    __shared__ unsigned short Xl[BROWS*XSTR];   // 16896 B
    __shared__ float Ps[NWAVE][BROWS];          // 1 KB layer-3 partials
    const int tid   = threadIdx.x;
    const int lane  = tid & 63;
    const int w     = __builtin_amdgcn_readfirstlane(tid >> 6);
    const int hg    = lane >> 5;
    const int r0    = blockIdx.x * BROWS;

    const bf16x8* wf = (const bf16x8*)g_wfrag;

    // ---- PHASE 0a: issue ALL x-tile loads back-to-back (one HBM latency, not 8) ----
    f32x4 xv[8];
    #pragma unroll
    for (int i = 0; i < 8; ++i){
        int idx = i*TPB + tid;            // 0..2047 float4 slots (= row*32 + kq)
        int row = idx >> 5, kq = idx & 31;
        f32x4 v = {0.f, 0.f, 0.f, 0.f};
        if (r0 + row < n) v = reinterpret_cast<const f32x4*>(node1)[(size_t)(r0+row)*32 + kq];
        xv[i] = v;
    }
    // ---- PHASE 0b: issue A-frags for layer 1 (drain under split+store) ----
    bf16x8 A1h[8], A1l[8];
    #pragma unroll
    for (int ks = 0; ks < 8; ++ks){
        A1h[ks] = wf[((0*8 + ks)*4 + w)*64 + lane];   // L=0,T=hi
        A1l[ks] = wf[((1*8 + ks)*4 + w)*64 + lane];   // L=0,T=lo
    }
    // pin x-tile registers: forces the 8 loads to complete HERE, not per-iteration
    #pragma unroll
    for (int i = 0; i < 8; ++i) asm volatile("" : "+v"(xv[i]));

    // ---- PHASE 0c: split + store to LDS (pure VALU + ds_write, no stalls) ----
    #pragma unroll
    for (int i = 0; i < 8; ++i){
        int idx = i*TPB + tid;
        int row = idx >> 5, kq = idx & 31;
        ushort4 hv, lv;
        split2(xv[i][0], hv.x, lv.x);
        split2(xv[i][1], hv.y, lv.y);
        split2(xv[i][2], hv.z, lv.z);
        split2(xv[i][3], hv.w, lv.w);
        *(ushort4*)&Xh[row*XSTR + kq*4] = hv;
        *(ushort4*)&Xl[row*XSTR + kq*4] = lv;
    }

    // pin A1 in registers
    #pragma unroll
    for (int ks = 0; ks < 8; ++ks){
        asm volatile("" : "+v"(A1h[ks]), "+v"(A1l[ks]));
    }
    __syncthreads();

    f32x16 acc[2];

    // ---- layer 1 ----
    layer_compute(A1h, A1l, Xh, Xl, g_b1p, acc, lane, w);

    // ---- A-frags for layer 2: issue + pin now; latency drains under writeback ----
    bf16x8 A2h[8], A2l[8];
    #pragma unroll
    for (int ks = 0; ks < 8; ++ks){
        A2h[ks] = wf[((2*8 + ks)*4 + w)*64 + lane];   // L=1,T=hi
        A2l[ks] = wf[((3*8 + ks)*4 + w)*64 + lane];   // L=1,T=lo
    }
    #pragma unroll
    for (int ks = 0; ks < 8; ++ks){
        asm volatile("" : "+v"(A2h[ks]), "+v"(A2l[ks]));
    }

    __syncthreads();   // everyone done READING X

    // relu + bf16-split writeback: wave w writes features [32w,32w+32) for all rows
    #pragma unroll
    for (int nt = 0; nt < 2; ++nt){
        const int row = nt*32 + (lane & 31);
        #pragma unroll
        for (int qq = 0; qq < 4; ++qq){
            const int c = w*32 + qq*8 + (hg<<2);
            ushort4 hv, lv;
            float v;
            v = fmaxf(acc[nt][qq*4+0], 0.f); split2(v, hv.x, lv.x);
            v = fmaxf(acc[nt][qq*4+1], 0.f); split2(v, hv.y, lv.y);
            v = fmaxf(acc[nt][qq*4+2], 0.f); split2(v, hv.z, lv.z);
            v = fmaxf(acc[nt][qq*4+3], 0.f); split2(v, hv.w, lv.w);
            *(ushort4*)&Xh[row*XSTR + c] = hv;
            *(ushort4*)&Xl[row*XSTR + c] = lv;
        }
    }
    __syncthreads();   // h1 fully written

    // ---- layer 2 ----
    layer_compute(A2h, A2l, Xh, Xl, b2, acc, lane, w);

    // ---- layer 3: per-wave partial over its 32 features ----
    float p[2] = {0.f, 0.f};
    #pragma unroll
    for (int qq = 0; qq < 4; ++qq){
        const float4 wv = *(const float4*)&W3[w*32 + qq*8 + (hg<<2)];
        #pragma unroll
        for (int nt = 0; nt < 2; ++nt){
            p[nt] = fmaf(fmaxf(acc[nt][qq*4+0], 0.f), wv.x, p[nt]);
            p[nt] = fmaf(fmaxf(acc[nt][qq*4+1], 0.f), wv.y, p[nt]);
            p[nt] = fmaf(fmaxf(acc[nt][qq*4+2], 0.f), wv.z, p[nt]);
            p[nt] = fmaf(fmaxf(acc[nt][qq*4+3], 0.f), wv.w, p[nt]);
        }
    }
    #pragma unroll
    for (int nt = 0; nt < 2; ++nt){
        p[nt] += __shfl_xor(p[nt], 32);
        if (lane < 32) Ps[w][nt*32 + lane] = p[nt];
    }
    __syncthreads();

    // ---- cross-wave feature reduction + per-block softmax stats (wave 0) ----
    if (w == 0){
        const int ra = r0 + lane;
        const bool va = ra < n;
        const float s = Ps[0][lane] + Ps[1][lane] + Ps[2][lane] + Ps[3][lane];
        if (va) out[ra] = s;
        float m = va ? s : -3.0e38f;
        #pragma unroll
        for (int off = 32; off > 0; off >>= 1) m = fmaxf(m, __shfl_xor(m, off));
        float e = va ? expf(s - m) : 0.f;
        #pragma unroll
        for (int off = 32; off > 0; off >>= 1) e += __shfl_xor(e, off);
        if (lane == 0){ g_pm[blockIdx.x] = m; g_ps[blockIdx.x] = e; }
    }
}

__global__ __launch_bounds__(1024)
void k_combine(int ng)
{
    __shared__ float red[17];
    const int tid = threadIdx.x, lane = tid & 63, wv = tid >> 6;

    float m = -3.0e38f;
    for (int i = tid; i < ng; i += 1024) m = fmaxf(m, g_pm[i]);
    #pragma unroll
    for (int off = 32; off > 0; off >>= 1) m = fmaxf(m, __shfl_xor(m, off));
    if (lane == 0) red[wv] = m;
    __syncthreads();
    if (tid < 64){
        float v = (lane < 16) ? red[lane] : -3.0e38f;
        #pragma unroll
        for (int off = 32; off > 0; off >>= 1) v = fmaxf(v, __shfl_xor(v, off));
        if (lane == 0) red[16] = v;
    }
    __syncthreads();
    m = red[16];

    float z = 0.f;
    for (int i = tid; i < ng; i += 1024) z += g_ps[i] * expf(g_pm[i] - m);
    #pragma unroll
    for (int off = 32; off > 0; off >>= 1) z += __shfl_xor(z, off);
    __syncthreads();
    if (lane == 0) red[wv] = z;
    __syncthreads();
    if (tid < 64){
        float v = (lane < 16) ? red[lane] : 0.f;
        #pragma unroll
        for (int off = 32; off > 0; off >>= 1) v += __shfl_xor(v, off);
        if (lane == 0){ g_m = m; g_invZ = 1.0f / v; }
    }
}

__global__ __launch_bounds__(256)
void k_norm(float* __restrict__ s, int n)
{
    const int i = blockIdx.x * 256 + threadIdx.x;
    const float m = g_m, r = g_invZ;
    const int n4 = n >> 2;
    if (i < n4){
        float4 v = reinterpret_cast<float4*>(s)[i];
        v.x = expf(v.x - m) * r;
        v.y = expf(v.y - m) * r;
        v.z = expf(v.z - m) * r;
        v.w = expf(v.w - m) * r;
        reinterpret_cast<float4*>(s)[i] = v;
    }
    const int rem = n - (n4 << 2);
    if (i < rem){
        int t = (n4 << 2) + i;
        s[t] = expf(s[t] - m) * r;
    }
}

extern "C" void kernel_launch(void* const* d_in, const int* in_sizes, int n_in,
                              void* d_out, int out_size, void* d_ws, size_t ws_size,
                              hipStream_t stream)
{
    const float* node1 = (const float*)d_in[0];
    const float* urep  = (const float*)d_in[1];
    const float* W1    = (const float*)d_in[3];
    const float* b1    = (const float*)d_in[4];
    const float* W2    = (const float*)d_in[5];
    const float* b2    = (const float*)d_in[6];
    const float* W3    = (const float*)d_in[7];
    float* out = (float*)d_out;

    const int n    = in_sizes[0] / DD;            // 200000
    const int nblk = (n + BROWS - 1) / BROWS;     // 3125
    const int ng   = nblk;

    k_wprep<<<dim3(32), dim3(256), 0, stream>>>(W1, W2);
    k_b1p<<<dim3(1), dim3(128), 0, stream>>>(W1, b1, urep);
    k_mlp<<<dim3(nblk), dim3(TPB), 0, stream>>>(node1, b2, W3, out, n);
    k_combine<<<dim3(1), dim3(1024), 0, stream>>>(ng);

    const int n4  = n >> 2;
    const int nb3 = (n4 + 255) / 256 > 0 ? (n4 + 255) / 256 : 1;
    k_norm<<<dim3(nb3), dim3(256), 0, stream>>>(out, n);
}